// Round 1
// baseline (284.593 us; speedup 1.0000x reference)
//
#include <hip/hip_runtime.h>
#include <hip/hip_bf16.h>
#include <cmath>

#define NB 8
#define CCH 8
#define FF 257
#define TT 1000
#define AD 512
#define EPSI 1.1920928955078125e-07f
#define EPS5 1e-05f

// pair indexing for Hermitian upper triangle (i<=j)
__host__ __device__ constexpr int PIDX(int i, int j) { return i * 8 - i * (i - 1) / 2 + (j - i); }        // 0..35
__host__ __device__ constexpr int QIDX(int i, int j) { return i * 7 - i * (i - 1) / 2 + (j - i - 1); }    // 0..27 (j>i)

// record layout per (n,f), stride 132 floats:
// [0..35] sum ms*Re(s_i conj s_j)  (i<=j)
// [36..63] sum ms*Im(s_i conj s_j) (i<j)
// [64..99] sum Re(s_i conj s_j)
// [100..127] sum Im(s_i conj s_j)
// [128] sum ms
#define REC_STRIDE 132

__device__ inline float wredsum(float v) {
#pragma unroll
    for (int o = 32; o; o >>= 1) v += __shfl_down(v, o, 64);
    return v;
}

__global__ __launch_bounds__(256, 2) void cov_kernel(const float* __restrict__ mask,
                                                     const float* __restrict__ xr,
                                                     const float* __restrict__ xi,
                                                     float* __restrict__ cov) {
    const int f = blockIdx.x;
    const int n = blockIdx.y;
    const int tid = threadIdx.x;

    __shared__ float mask_lds[TT];
    __shared__ float wmax[4];
    __shared__ float acc_lds[4][129];

    // pass 1: stage mask column + compute max|mask|
    float m = 0.f;
    for (int t = tid; t < TT; t += 256) {
        float mv = mask[(size_t)(n * TT + t) * FF + f];
        mask_lds[t] = mv;
        m = fmaxf(m, fabsf(mv));
    }
#pragma unroll
    for (int o = 32; o; o >>= 1) m = fmaxf(m, __shfl_down(m, o, 64));
    if ((tid & 63) == 0) wmax[tid >> 6] = m;
    __syncthreads();
    const float inv_mx = 1.0f / (fmaxf(fmaxf(wmax[0], wmax[1]), fmaxf(wmax[2], wmax[3])) + EPSI);

    float sr[36] = {};
    float si[28] = {};
    float tr_[36] = {};
    float ti[28] = {};
    float sm = 0.f;

    const size_t cstride = (size_t)FF * TT;
    const float* xrb = xr + ((size_t)(n * CCH) * FF + f) * TT;
    const float* xib = xi + ((size_t)(n * CCH) * FF + f) * TT;

    for (int t = tid; t < TT; t += 256) {
        float ar[8], ai[8];
#pragma unroll
        for (int c = 0; c < 8; c++) {
            ar[c] = xrb[c * cstride + t];
            ai[c] = xib[c * cstride + t];
        }
        float msv = mask_lds[t] * inv_mx;
        sm += msv;
#pragma unroll
        for (int i = 0; i < 8; i++) {
            {
                float pr = ar[i] * ar[i] + ai[i] * ai[i];
                tr_[PIDX(i, i)] += pr;
                sr[PIDX(i, i)] += msv * pr;
            }
#pragma unroll
            for (int j = i + 1; j < 8; j++) {
                float pr = ar[i] * ar[j] + ai[i] * ai[j];
                float pi = ai[i] * ar[j] - ar[i] * ai[j];
                tr_[PIDX(i, j)] += pr;
                ti[QIDX(i, j)] += pi;
                sr[PIDX(i, j)] += msv * pr;
                si[QIDX(i, j)] += msv * pi;
            }
        }
    }

    const int lane = tid & 63, wv = tid >> 6;
#pragma unroll
    for (int p = 0; p < 36; p++) { float v = wredsum(sr[p]); if (!lane) acc_lds[wv][p] = v; }
#pragma unroll
    for (int q = 0; q < 28; q++) { float v = wredsum(si[q]); if (!lane) acc_lds[wv][36 + q] = v; }
#pragma unroll
    for (int p = 0; p < 36; p++) { float v = wredsum(tr_[p]); if (!lane) acc_lds[wv][64 + p] = v; }
#pragma unroll
    for (int q = 0; q < 28; q++) { float v = wredsum(ti[q]); if (!lane) acc_lds[wv][100 + q] = v; }
    { float v = wredsum(sm); if (!lane) acc_lds[wv][128] = v; }
    __syncthreads();

    float* recout = cov + (size_t)(n * FF + f) * REC_STRIDE;
    for (int s = tid; s < 129; s += 256)
        recout[s] = acc_lds[0][s] + acc_lds[1][s] + acc_lds[2][s] + acc_lds[3][s];
}

__global__ void attn_kernel(const float* __restrict__ cov,
                            const float* __restrict__ proj_w,
                            const float* __restrict__ proj_b,
                            const float* __restrict__ gvec_w,
                            const float* __restrict__ gvec_b,
                            float* __restrict__ u) {
    const int n = blockIdx.x;
    const int tid = threadIdx.x;
    __shared__ float feat[8][FF];
    __shared__ float gred[4][8];

    for (int f = tid; f < FF; f += 256) {
        const float* rec = cov + (size_t)(n * FF + f) * REC_STRIDE;
        float den_s = fmaxf(rec[128], EPSI);
        float scale = 1.0f / (7.0f * den_s);
#pragma unroll
        for (int i = 0; i < 8; i++) {
            float rr = 0.f, ri = 0.f;
#pragma unroll
            for (int j = 0; j < 8; j++) {
                if (j == i) continue;
                if (j > i) { rr += rec[PIDX(i, j)]; ri += rec[36 + QIDX(i, j)]; }
                else       { rr += rec[PIDX(j, i)]; ri -= rec[36 + QIDX(j, i)]; }
            }
            feat[i][f] = sqrtf(rr * rr + ri * ri) * scale;
        }
    }
    __syncthreads();

    float gacc[8] = {};
    for (int d = tid; d < AD; d += 256) {
        float acc[8];
        float pb = proj_b[d];
#pragma unroll
        for (int c = 0; c < 8; c++) acc[c] = pb;
        const float* pw = proj_w + (size_t)d * FF;
        for (int f = 0; f < FF; f++) {
            float w = pw[f];
#pragma unroll
            for (int c = 0; c < 8; c++) acc[c] += w * feat[c][f];
        }
        float gw = gvec_w[d];
#pragma unroll
        for (int c = 0; c < 8; c++) gacc[c] += gw * tanhf(acc[c]);
    }
    const int lane = tid & 63, wv = tid >> 6;
#pragma unroll
    for (int c = 0; c < 8; c++) {
        float v = wredsum(gacc[c]);
        if (!lane) gred[wv][c] = v;
    }
    __syncthreads();
    if (tid == 0) {
        float g[8];
        float mx = -1e30f;
#pragma unroll
        for (int c = 0; c < 8; c++) {
            g[c] = gred[0][c] + gred[1][c] + gred[2][c] + gred[3][c] + gvec_b[0];
            mx = fmaxf(mx, g[c]);
        }
        float s = 0.f;
#pragma unroll
        for (int c = 0; c < 8; c++) { g[c] = expf(g[c] - mx); s += g[c]; }
        float is = 1.0f / s;
#pragma unroll
        for (int c = 0; c < 8; c++) u[n * 8 + c] = g[c] * is;
    }
}

__global__ __launch_bounds__(64, 1) void solve_kernel(const float* __restrict__ cov,
                                                      const float* __restrict__ u,
                                                      float* __restrict__ wout) {
    const int idx = blockIdx.x * 64 + threadIdx.x;
    if (idx >= NB * FF) return;
    const int n = idx / FF;
    const float* rec = cov + (size_t)idx * REC_STRIDE;

    float smv = rec[128];
    float inv_s = 1.0f / fmaxf(smv, EPSI);
    float inv_n = 1.0f / fmaxf((float)TT - smv, EPSI);

    float Ar[8][8], Ai[8][8], Br[8][8], Bi[8][8];  // A = Rn, B = Rs -> X
#pragma unroll
    for (int i = 0; i < 8; i++) {
#pragma unroll
        for (int j = i; j < 8; j++) {
            float s_r = rec[PIDX(i, j)] * inv_s;
            float t_r = rec[64 + PIDX(i, j)];
            float n_r = (t_r - rec[PIDX(i, j)]) * inv_n;
            if (j == i) {
                Br[i][i] = s_r; Bi[i][i] = 0.f;
                Ar[i][i] = n_r + EPS5; Ai[i][i] = 0.f;
            } else {
                float s_i = rec[36 + QIDX(i, j)] * inv_s;
                float n_i = (rec[100 + QIDX(i, j)] - rec[36 + QIDX(i, j)]) * inv_n;
                Br[i][j] = s_r; Bi[i][j] = s_i;
                Br[j][i] = s_r; Bi[j][i] = -s_i;
                Ar[i][j] = n_r; Ai[i][j] = n_i;
                Ar[j][i] = n_r; Ai[j][i] = -n_i;
            }
        }
    }

    // forward elimination (no pivot: A is HPD + eps*I)
#pragma unroll
    for (int k = 0; k < 8; k++) {
        float dr = Ar[k][k], di = Ai[k][k];
        float iv = 1.0f / (dr * dr + di * di);
        float pir = dr * iv, pii = -di * iv;
#pragma unroll
        for (int r = k + 1; r < 8; r++) {
            float ar = Ar[r][k], ai = Ai[r][k];
            float fr = ar * pir - ai * pii;
            float fi = ar * pii + ai * pir;
#pragma unroll
            for (int j = k + 1; j < 8; j++) {
                Ar[r][j] -= fr * Ar[k][j] - fi * Ai[k][j];
                Ai[r][j] -= fr * Ai[k][j] + fi * Ar[k][j];
            }
#pragma unroll
            for (int j = 0; j < 8; j++) {
                Br[r][j] -= fr * Br[k][j] - fi * Bi[k][j];
                Bi[r][j] -= fr * Bi[k][j] + fi * Br[k][j];
            }
        }
    }
    // back substitution: X into B
#pragma unroll
    for (int k = 7; k >= 0; k--) {
        float dr = Ar[k][k], di = Ai[k][k];
        float iv = 1.0f / (dr * dr + di * di);
        float pir = dr * iv, pii = -di * iv;
#pragma unroll
        for (int j = 0; j < 8; j++) {
            float s_r = Br[k][j], s_i = Bi[k][j];
#pragma unroll
            for (int m = k + 1; m < 8; m++) {
                s_r -= Ar[k][m] * Br[m][j] - Ai[k][m] * Bi[m][j];
                s_i -= Ar[k][m] * Bi[m][j] + Ai[k][m] * Br[m][j];
            }
            Br[k][j] = s_r * pir - s_i * pii;
            Bi[k][j] = s_r * pii + s_i * pir;
        }
    }

    float trr = EPS5, tri = 0.f;
#pragma unroll
    for (int i = 0; i < 8; i++) { trr += Br[i][i]; tri += Bi[i][i]; }
    float tinv = 1.0f / (trr * trr + tri * tri);

    float* wo = wout + (size_t)idx * 16;
#pragma unroll
    for (int i = 0; i < 8; i++) {
        float nr = 0.f, ni = 0.f;
#pragma unroll
        for (int c = 0; c < 8; c++) {
            float uc = u[n * 8 + c];
            nr += Br[i][c] * uc;
            ni += Bi[i][c] * uc;
        }
        float wr = (nr * trr + ni * tri) * tinv;
        float wi = (ni * trr - nr * tri) * tinv;
        wo[i * 2] = wr;        // store conj(w): real
        wo[i * 2 + 1] = -wi;   // store conj(w): imag
    }
}

__global__ __launch_bounds__(256) void beam_kernel(const float* __restrict__ xr,
                                                   const float* __restrict__ xi,
                                                   const float* __restrict__ wc,
                                                   float* __restrict__ out) {
    const int n = blockIdx.z;
    const int f0 = blockIdx.y * 32;
    const int t0 = blockIdx.x * 64;
    const int tid = threadIdx.x;

    __shared__ float wlds[32][16];
    __shared__ float bldr[32][65];
    __shared__ float bldi[32][65];

    for (int s = tid; s < 32 * 16; s += 256) {
        int fl = s >> 4, rest = s & 15;
        int f = f0 + fl;
        wlds[fl][rest] = (f < FF) ? wc[(size_t)(n * FF + f) * 16 + rest] : 0.f;
    }
    __syncthreads();

    const int lane_t = tid & 63, row = tid >> 6;
    const int t = t0 + lane_t;
    const bool tok = t < TT;
    const size_t cstride = (size_t)FF * TT;

#pragma unroll
    for (int k = 0; k < 8; k++) {
        int fl = row + k * 4;
        int f = f0 + fl;
        float br = 0.f, bi = 0.f;
        if (f < FF && tok) {
            size_t base = ((size_t)(n * CCH) * FF + f) * TT + t;
#pragma unroll
            for (int c = 0; c < 8; c++) {
                float vr = xr[base + c * cstride];
                float vi = xi[base + c * cstride];
                float wr = wlds[fl][c * 2], wi_ = wlds[fl][c * 2 + 1];
                br += wr * vr - wi_ * vi;
                bi += wr * vi + wi_ * vr;
            }
        }
        bldr[fl][lane_t] = br;
        bldi[fl][lane_t] = bi;
    }
    __syncthreads();

    const int fc = tid & 31, trb = tid >> 5;
    const int f = f0 + fc;
    float2* outv = (float2*)out;
#pragma unroll
    for (int k = 0; k < 8; k++) {
        int tr = trb + k * 8;
        int t2 = t0 + tr;
        if (f < FF && t2 < TT) {
            float2 v = make_float2(bldr[fc][tr], bldi[fc][tr]);
            outv[(size_t)(n * TT + t2) * FF + f] = v;
        }
    }
}

extern "C" void kernel_launch(void* const* d_in, const int* in_sizes, int n_in,
                              void* d_out, int out_size, void* d_ws, size_t ws_size,
                              hipStream_t stream) {
    const float* mask = (const float*)d_in[0];
    const float* xr = (const float*)d_in[1];
    const float* xi = (const float*)d_in[2];
    const float* pw = (const float*)d_in[3];
    const float* pb = (const float*)d_in[4];
    const float* gw = (const float*)d_in[5];
    const float* gb = (const float*)d_in[6];
    float* out = (float*)d_out;
    float* ws = (float*)d_ws;

    float* cov = ws;                                   // 2056 * 132
    float* u = ws + (size_t)NB * FF * REC_STRIDE;      // 64
    float* wv = u + 64;                                // 2056 * 16

    hipLaunchKernelGGL(cov_kernel, dim3(FF, NB), dim3(256), 0, stream, mask, xr, xi, cov);
    hipLaunchKernelGGL(attn_kernel, dim3(NB), dim3(256), 0, stream, cov, pw, pb, gw, gb, u);
    hipLaunchKernelGGL(solve_kernel, dim3((NB * FF + 63) / 64), dim3(64), 0, stream, cov, u, wv);
    hipLaunchKernelGGL(beam_kernel, dim3((TT + 63) / 64, (FF + 31) / 32, NB), dim3(256), 0, stream, xr, xi, wv, out);
}

// Round 2
// 190.802 us; speedup vs baseline: 1.4916x; 1.4916x over previous
//
#include <hip/hip_runtime.h>
#include <hip/hip_bf16.h>
#include <cmath>

#define NB 8
#define CCH 8
#define FF 257
#define TT 1000
#define AD 512
#define EPSI 1.1920928955078125e-07f
#define EPS5 1e-05f
#define TILE_T 256

// pair indexing for Hermitian upper triangle (i<=j)
__host__ __device__ constexpr int PIDX(int i, int j) { return i * 8 - i * (i - 1) / 2 + (j - i); }        // 0..35
__host__ __device__ constexpr int QIDX(int i, int j) { return i * 7 - i * (i - 1) / 2 + (j - i - 1); }    // 0..27 (j>i)

// record layout per (n,f), stride 132 floats:
// [0..35] sum ms*Re(s_i conj s_j)  (i<=j)
// [36..63] sum ms*Im(s_i conj s_j) (i<j)
// [64..99] sum Re(s_i conj s_j)
// [100..127] sum Im(s_i conj s_j)
// [128] sum ms
#define REC_STRIDE 132

__device__ inline float wredsum(float v) {
#pragma unroll
    for (int o = 32; o; o >>= 1) v += __shfl_down(v, o, 64);
    return v;
}

// Block = (n,f). Threads 0-127: masked sums. Threads 128-255: unmasked sums.
// x tile staged in LDS (float4 loads) so both halves share one HBM read.
__global__ __launch_bounds__(256) void cov_kernel(const float* __restrict__ mask,
                                                  const float* __restrict__ xr,
                                                  const float* __restrict__ xi,
                                                  float* __restrict__ cov) {
    const int f = blockIdx.x;
    const int n = blockIdx.y;
    const int tid = threadIdx.x;

    __shared__ float mask_lds[TT];
    __shared__ float wmax[4];
    __shared__ float xldsr[8][TILE_T];
    __shared__ float xldsi[8][TILE_T];
    __shared__ float red4[4][65];

    // phase 0: stage mask column + max|mask|
    float m = 0.f;
    for (int t = tid; t < TT; t += 256) {
        float mv = mask[(size_t)(n * TT + t) * FF + f];
        mask_lds[t] = mv;
        m = fmaxf(m, fabsf(mv));
    }
#pragma unroll
    for (int o = 32; o; o >>= 1) m = fmaxf(m, __shfl_down(m, o, 64));
    if ((tid & 63) == 0) wmax[tid >> 6] = m;
    __syncthreads();
    const float inv_mx = 1.0f / (fmaxf(fmaxf(wmax[0], wmax[1]), fmaxf(wmax[2], wmax[3])) + EPSI);

    const int grp = tid >> 7;   // 0: masked, 1: unmasked
    const int tl = tid & 127;

    float accR[36] = {};
    float accI[28] = {};
    float sm = 0.f;

    const size_t cstride = (size_t)FF * TT;
    const float* xrb = xr + ((size_t)(n * CCH) * FF + f) * TT;
    const float* xib = xi + ((size_t)(n * CCH) * FF + f) * TT;

    for (int t0 = 0; t0 < TT; t0 += TILE_T) {
        const int nt = min(TILE_T, TT - t0);
        // stage tile: 8 ch x nt, real+imag, float4 per thread-slot
        for (int s = tid; s < 8 * (TILE_T / 4); s += 256) {
            int c = s >> 6;            // TILE_T/4 = 64 quads per channel
            int tq = (s & 63) * 4;
            if (tq < nt) {
                *(float4*)&xldsr[c][tq] = *(const float4*)&xrb[c * cstride + t0 + tq];
                *(float4*)&xldsi[c][tq] = *(const float4*)&xib[c * cstride + t0 + tq];
            }
        }
        __syncthreads();

        for (int tt = tl; tt < nt; tt += 128) {
            float ar[8], ai[8];
#pragma unroll
            for (int c = 0; c < 8; c++) {
                ar[c] = xldsr[c][tt];
                ai[c] = xldsi[c][tt];
            }
            float w;
            if (grp == 0) {
                w = mask_lds[t0 + tt] * inv_mx;
                sm += w;
            } else {
                w = 1.0f;
            }
#pragma unroll
            for (int i = 0; i < 8; i++) {
                {
                    float pr = ar[i] * ar[i] + ai[i] * ai[i];
                    accR[PIDX(i, i)] += w * pr;
                }
#pragma unroll
                for (int j = i + 1; j < 8; j++) {
                    float pr = ar[i] * ar[j] + ai[i] * ai[j];
                    float pi = ai[i] * ar[j] - ar[i] * ai[j];
                    accR[PIDX(i, j)] += w * pr;
                    accI[QIDX(i, j)] += w * pi;
                }
            }
        }
        __syncthreads();
    }

    const int lane = tid & 63, wv = tid >> 6;  // waves 0,1 = grp0; 2,3 = grp1
#pragma unroll
    for (int p = 0; p < 36; p++) { float v = wredsum(accR[p]); if (!lane) red4[wv][p] = v; }
#pragma unroll
    for (int q = 0; q < 28; q++) { float v = wredsum(accI[q]); if (!lane) red4[wv][36 + q] = v; }
    { float v = wredsum(sm); if (!lane) red4[wv][64] = v; }
    __syncthreads();

    float* recout = cov + (size_t)(n * FF + f) * REC_STRIDE;
    if (tid < 64) recout[tid] = red4[0][tid] + red4[1][tid];
    else if (tid < 128) recout[tid] = red4[2][tid - 64] + red4[3][tid - 64];
    else if (tid == 128) recout[128] = red4[0][64] + red4[1][64];
}

__global__ void attn_kernel(const float* __restrict__ cov,
                            const float* __restrict__ proj_w,
                            const float* __restrict__ proj_b,
                            const float* __restrict__ gvec_w,
                            const float* __restrict__ gvec_b,
                            float* __restrict__ u) {
    const int n = blockIdx.x;
    const int tid = threadIdx.x;
    __shared__ float feat[8][FF];
    __shared__ float gred[4][8];

    for (int f = tid; f < FF; f += 256) {
        const float* rec = cov + (size_t)(n * FF + f) * REC_STRIDE;
        float den_s = fmaxf(rec[128], EPSI);
        float scale = 1.0f / (7.0f * den_s);
#pragma unroll
        for (int i = 0; i < 8; i++) {
            float rr = 0.f, ri = 0.f;
#pragma unroll
            for (int j = 0; j < 8; j++) {
                if (j == i) continue;
                if (j > i) { rr += rec[PIDX(i, j)]; ri += rec[36 + QIDX(i, j)]; }
                else       { rr += rec[PIDX(j, i)]; ri -= rec[36 + QIDX(j, i)]; }
            }
            feat[i][f] = sqrtf(rr * rr + ri * ri) * scale;
        }
    }
    __syncthreads();

    float gacc[8] = {};
    for (int d = tid; d < AD; d += 256) {
        float acc[8];
        float pb = proj_b[d];
#pragma unroll
        for (int c = 0; c < 8; c++) acc[c] = pb;
        const float* pw = proj_w + (size_t)d * FF;
        for (int f = 0; f < FF; f++) {
            float w = pw[f];
#pragma unroll
            for (int c = 0; c < 8; c++) acc[c] += w * feat[c][f];
        }
        float gw = gvec_w[d];
#pragma unroll
        for (int c = 0; c < 8; c++) gacc[c] += gw * tanhf(acc[c]);
    }
    const int lane = tid & 63, wv = tid >> 6;
#pragma unroll
    for (int c = 0; c < 8; c++) {
        float v = wredsum(gacc[c]);
        if (!lane) gred[wv][c] = v;
    }
    __syncthreads();
    if (tid == 0) {
        float g[8];
        float mx = -1e30f;
#pragma unroll
        for (int c = 0; c < 8; c++) {
            g[c] = gred[0][c] + gred[1][c] + gred[2][c] + gred[3][c] + gvec_b[0];
            mx = fmaxf(mx, g[c]);
        }
        float s = 0.f;
#pragma unroll
        for (int c = 0; c < 8; c++) { g[c] = expf(g[c] - mx); s += g[c]; }
        float is = 1.0f / s;
#pragma unroll
        for (int c = 0; c < 8; c++) u[n * 8 + c] = g[c] * is;
    }
}

__global__ __launch_bounds__(64, 1) void solve_kernel(const float* __restrict__ cov,
                                                      const float* __restrict__ u,
                                                      float* __restrict__ wout) {
    const int idx = blockIdx.x * 64 + threadIdx.x;
    if (idx >= NB * FF) return;
    const int n = idx / FF;
    const float* rec = cov + (size_t)idx * REC_STRIDE;

    float smv = rec[128];
    float inv_s = 1.0f / fmaxf(smv, EPSI);
    float inv_n = 1.0f / fmaxf((float)TT - smv, EPSI);

    float Ar[8][8], Ai[8][8], Br[8][8], Bi[8][8];  // A = Rn, B = Rs -> X
#pragma unroll
    for (int i = 0; i < 8; i++) {
#pragma unroll
        for (int j = i; j < 8; j++) {
            float s_r = rec[PIDX(i, j)] * inv_s;
            float t_r = rec[64 + PIDX(i, j)];
            float n_r = (t_r - rec[PIDX(i, j)]) * inv_n;
            if (j == i) {
                Br[i][i] = s_r; Bi[i][i] = 0.f;
                Ar[i][i] = n_r + EPS5; Ai[i][i] = 0.f;
            } else {
                float s_i = rec[36 + QIDX(i, j)] * inv_s;
                float n_i = (rec[100 + QIDX(i, j)] - rec[36 + QIDX(i, j)]) * inv_n;
                Br[i][j] = s_r; Bi[i][j] = s_i;
                Br[j][i] = s_r; Bi[j][i] = -s_i;
                Ar[i][j] = n_r; Ai[i][j] = n_i;
                Ar[j][i] = n_r; Ai[j][i] = -n_i;
            }
        }
    }

    // forward elimination (no pivot: A is HPD + eps*I)
#pragma unroll
    for (int k = 0; k < 8; k++) {
        float dr = Ar[k][k], di = Ai[k][k];
        float iv = 1.0f / (dr * dr + di * di);
        float pir = dr * iv, pii = -di * iv;
#pragma unroll
        for (int r = k + 1; r < 8; r++) {
            float ar = Ar[r][k], ai = Ai[r][k];
            float fr = ar * pir - ai * pii;
            float fi = ar * pii + ai * pir;
#pragma unroll
            for (int j = k + 1; j < 8; j++) {
                Ar[r][j] -= fr * Ar[k][j] - fi * Ai[k][j];
                Ai[r][j] -= fr * Ai[k][j] + fi * Ar[k][j];
            }
#pragma unroll
            for (int j = 0; j < 8; j++) {
                Br[r][j] -= fr * Br[k][j] - fi * Bi[k][j];
                Bi[r][j] -= fr * Bi[k][j] + fi * Br[k][j];
            }
        }
    }
    // back substitution: X into B
#pragma unroll
    for (int k = 7; k >= 0; k--) {
        float dr = Ar[k][k], di = Ai[k][k];
        float iv = 1.0f / (dr * dr + di * di);
        float pir = dr * iv, pii = -di * iv;
#pragma unroll
        for (int j = 0; j < 8; j++) {
            float s_r = Br[k][j], s_i = Bi[k][j];
#pragma unroll
            for (int m = k + 1; m < 8; m++) {
                s_r -= Ar[k][m] * Br[m][j] - Ai[k][m] * Bi[m][j];
                s_i -= Ar[k][m] * Bi[m][j] + Ai[k][m] * Br[m][j];
            }
            Br[k][j] = s_r * pir - s_i * pii;
            Bi[k][j] = s_r * pii + s_i * pir;
        }
    }

    float trr = EPS5, tri = 0.f;
#pragma unroll
    for (int i = 0; i < 8; i++) { trr += Br[i][i]; tri += Bi[i][i]; }
    float tinv = 1.0f / (trr * trr + tri * tri);

    float* wo = wout + (size_t)idx * 16;
#pragma unroll
    for (int i = 0; i < 8; i++) {
        float nr = 0.f, ni = 0.f;
#pragma unroll
        for (int c = 0; c < 8; c++) {
            float uc = u[n * 8 + c];
            nr += Br[i][c] * uc;
            ni += Bi[i][c] * uc;
        }
        float wr = (nr * trr + ni * tri) * tinv;
        float wi = (ni * trr - nr * tri) * tinv;
        wo[i * 2] = wr;        // store conj(w): real
        wo[i * 2 + 1] = -wi;   // store conj(w): imag
    }
}

__global__ __launch_bounds__(256) void beam_kernel(const float* __restrict__ xr,
                                                   const float* __restrict__ xi,
                                                   const float* __restrict__ wc,
                                                   float* __restrict__ out) {
    const int n = blockIdx.z;
    const int f0 = blockIdx.y * 32;
    const int t0 = blockIdx.x * 64;
    const int tid = threadIdx.x;

    __shared__ float wlds[32][16];
    __shared__ float bldr[32][65];
    __shared__ float bldi[32][65];

    for (int s = tid; s < 32 * 16; s += 256) {
        int fl = s >> 4, rest = s & 15;
        int f = f0 + fl;
        wlds[fl][rest] = (f < FF) ? wc[(size_t)(n * FF + f) * 16 + rest] : 0.f;
    }
    __syncthreads();

    const int lane_t = tid & 63, row = tid >> 6;
    const int t = t0 + lane_t;
    const bool tok = t < TT;
    const size_t cstride = (size_t)FF * TT;

#pragma unroll
    for (int k = 0; k < 8; k++) {
        int fl = row + k * 4;
        int f = f0 + fl;
        float br = 0.f, bi = 0.f;
        if (f < FF && tok) {
            size_t base = ((size_t)(n * CCH) * FF + f) * TT + t;
#pragma unroll
            for (int c = 0; c < 8; c++) {
                float vr = xr[base + c * cstride];
                float vi = xi[base + c * cstride];
                float wr = wlds[fl][c * 2], wi_ = wlds[fl][c * 2 + 1];
                br += wr * vr - wi_ * vi;
                bi += wr * vi + wi_ * vr;
            }
        }
        bldr[fl][lane_t] = br;
        bldi[fl][lane_t] = bi;
    }
    __syncthreads();

    const int fc = tid & 31, trb = tid >> 5;
    const int f = f0 + fc;
    float2* outv = (float2*)out;
#pragma unroll
    for (int k = 0; k < 8; k++) {
        int tr = trb + k * 8;
        int t2 = t0 + tr;
        if (f < FF && t2 < TT) {
            float2 v = make_float2(bldr[fc][tr], bldi[fc][tr]);
            outv[(size_t)(n * TT + t2) * FF + f] = v;
        }
    }
}

extern "C" void kernel_launch(void* const* d_in, const int* in_sizes, int n_in,
                              void* d_out, int out_size, void* d_ws, size_t ws_size,
                              hipStream_t stream) {
    const float* mask = (const float*)d_in[0];
    const float* xr = (const float*)d_in[1];
    const float* xi = (const float*)d_in[2];
    const float* pw = (const float*)d_in[3];
    const float* pb = (const float*)d_in[4];
    const float* gw = (const float*)d_in[5];
    const float* gb = (const float*)d_in[6];
    float* out = (float*)d_out;
    float* ws = (float*)d_ws;

    float* cov = ws;                                   // 2056 * 132
    float* u = ws + (size_t)NB * FF * REC_STRIDE;      // 64
    float* wv = u + 64;                                // 2056 * 16

    hipLaunchKernelGGL(cov_kernel, dim3(FF, NB), dim3(256), 0, stream, mask, xr, xi, cov);
    hipLaunchKernelGGL(attn_kernel, dim3(NB), dim3(256), 0, stream, cov, pw, pb, gw, gb, u);
    hipLaunchKernelGGL(solve_kernel, dim3((NB * FF + 63) / 64), dim3(64), 0, stream, cov, u, wv);
    hipLaunchKernelGGL(beam_kernel, dim3((TT + 63) / 64, (FF + 31) / 32, NB), dim3(256), 0, stream, xr, xi, wv, out);
}